// Round 3
// baseline (160.190 us; speedup 1.0000x reference)
//
#include <hip/hip_runtime.h>

// LengthRegulator: out[b, t, :] = x[b, j, :] where j = searchsorted(cumsum(dur[b]), t, 'right'),
// zero for t >= total duration. B=16, L=512, D=512, T_MAX=4096. fp32 in/out.

#define BATCH 16
#define LTOK  512
#define DIM   512
#define TMAX  4096

// Kernel 1: per-batch inclusive cumsum of duration_tokens -> ends[B][L] in workspace.
__global__ __launch_bounds__(LTOK) void MRTE_cumsum_kernel(const int* __restrict__ dur,
                                                           int* __restrict__ ends) {
    __shared__ int s[LTOK];
    const int b   = blockIdx.x;
    const int tid = threadIdx.x;
    s[tid] = dur[b * LTOK + tid];
    __syncthreads();
    // Hillis-Steele inclusive scan over 512 elements
    #pragma unroll
    for (int off = 1; off < LTOK; off <<= 1) {
        int v = (tid >= off) ? s[tid - off] : 0;
        __syncthreads();
        s[tid] += v;
        __syncthreads();
    }
    ends[b * LTOK + tid] = s[tid];
}

// Kernel 2: one block per output frame (b, t). Block-uniform binary search for the
// covering token (full lower_bound: run until lo==hi — R1's fixed 9 steps left the
// final size-1 cell untested, an off-by-one), then coalesced float4 row copy.
__global__ __launch_bounds__(128) void MRTE_gather_kernel(const float* __restrict__ x,
                                                          const int* __restrict__ ends,
                                                          float* __restrict__ out) {
    const int t   = blockIdx.x;
    const int b   = blockIdx.y;
    const int tid = threadIdx.x;

    const int* __restrict__ e = ends + b * LTOK;
    const int total = e[LTOK - 1];

    float4* __restrict__ orow =
        reinterpret_cast<float4*>(out + ((size_t)b * TMAX + (size_t)t) * DIM);

    if (t >= total) {
        orow[tid] = make_float4(0.f, 0.f, 0.f, 0.f);
        return;
    }

    // first j with e[j] > t  (uniform across the block; loads broadcast from cache)
    int lo = 0, hi = LTOK;
    while (lo < hi) {
        int mid = (lo + hi) >> 1;
        if (e[mid] > t) hi = mid; else lo = mid + 1;
    }

    const float4* __restrict__ xrow =
        reinterpret_cast<const float4*>(x + ((size_t)b * LTOK + (size_t)lo) * DIM);
    orow[tid] = xrow[tid];
}

extern "C" void kernel_launch(void* const* d_in, const int* in_sizes, int n_in,
                              void* d_out, int out_size, void* d_ws, size_t ws_size,
                              hipStream_t stream) {
    const float* x   = (const float*)d_in[0];        // [B, L, D] fp32
    const int*   dur = (const int*)d_in[1];          // [B, L] int32
    // d_in[2] = mel_max_length scalar (static 4096; hard-coded)
    float* out = (float*)d_out;                       // [B, TMAX, D] fp32
    int*   ends = (int*)d_ws;                         // [B, L] int32 (32 KB scratch)

    MRTE_cumsum_kernel<<<BATCH, LTOK, 0, stream>>>(dur, ends);
    MRTE_gather_kernel<<<dim3(TMAX, BATCH), 128, 0, stream>>>(x, ends, out);
}

// Round 5
// 159.275 us; speedup vs baseline: 1.0057x; 1.0057x over previous
//
#include <hip/hip_runtime.h>

// LengthRegulator: out[b, t, :] = x[b, j, :] where j = searchsorted(cumsum(dur[b]), t, 'right'),
// zero for t >= total duration. B=16, L=512, D=512, T_MAX=4096. fp32 in/out.
// R5 = R4 with the nontemporal store fixed to use a native clang vector type
// (__builtin_nontemporal_store rejects HIP_vector_type float4).

#define BATCH 16
#define LTOK  512
#define DIM   512
#define TMAX  4096
#define ROWS  8   // output rows per gather block

typedef float nt_f4 __attribute__((ext_vector_type(4)));  // 16B, same layout as float4

// Kernel 1: per-batch inclusive cumsum of duration_tokens -> ends[B][L].
// 512 threads = 8 waves: shfl inclusive scan per wave, then wave-sum offsets via LDS.
__global__ __launch_bounds__(512) void MRTE_cumsum_kernel(const int* __restrict__ dur,
                                                          int* __restrict__ ends) {
    const int b    = blockIdx.x;
    const int tid  = threadIdx.x;
    const int lane = tid & 63;
    const int wid  = tid >> 6;
    __shared__ int wsum[8];

    int v = dur[b * LTOK + tid];
    #pragma unroll
    for (int off = 1; off < 64; off <<= 1) {
        int n = __shfl_up(v, off, 64);
        if (lane >= off) v += n;
    }
    if (lane == 63) wsum[wid] = v;
    __syncthreads();
    int add = 0;
    #pragma unroll
    for (int w = 0; w < 7; ++w)
        add += (w < wid) ? wsum[w] : 0;
    ends[b * LTOK + tid] = v + add;
}

// Kernel 2: one 256-thread block per (b, 8-row chunk). Stage ends[512] in LDS,
// one block-uniform binary search for the chunk's first token, per-thread
// incremental advance for subsequent rows (monotone). Two rows written per
// iteration (halves of the block), 16B lanes, nontemporal streaming stores.
__global__ __launch_bounds__(256) void MRTE_gather_kernel(const float* __restrict__ x,
                                                          const int* __restrict__ ends,
                                                          float* __restrict__ out) {
    __shared__ int se[LTOK];
    const int b    = blockIdx.y;
    const int t0   = blockIdx.x * ROWS;
    const int tid  = threadIdx.x;
    const int half = tid >> 7;    // 0 or 1: which row of the pair
    const int lane = tid & 127;   // 16B column (128 * 16B = 2KB row)

    se[tid]       = ends[b * LTOK + tid];
    se[tid + 256] = ends[b * LTOK + tid + 256];
    __syncthreads();

    const int total = se[LTOK - 1];

    // first j with se[j] > t0 (block-uniform; LDS broadcast reads)
    int lo = 0, hi = LTOK;
    while (lo < hi) {
        int mid = (lo + hi) >> 1;
        if (se[mid] > t0) hi = mid; else lo = mid + 1;
    }

    const nt_f4* __restrict__ xb =
        reinterpret_cast<const nt_f4*>(x + (size_t)b * LTOK * DIM);
    nt_f4* __restrict__ ob =
        reinterpret_cast<nt_f4*>(out + ((size_t)b * TMAX + (size_t)t0) * DIM);

    int jt = lo;  // per-thread token cursor, monotone over this thread's rows
    #pragma unroll
    for (int r = 0; r < ROWS; r += 2) {
        const int t = t0 + r + half;
        nt_f4 v = (nt_f4)0.f;
        if (t < total) {
            while (se[jt] <= t) ++jt;          // avg ~2 LDS-hit steps per chunk
            v = xb[(size_t)jt * (DIM / 4) + lane];
        }
        __builtin_nontemporal_store(v, &ob[(size_t)(r + half) * (DIM / 4) + lane]);
    }
}

extern "C" void kernel_launch(void* const* d_in, const int* in_sizes, int n_in,
                              void* d_out, int out_size, void* d_ws, size_t ws_size,
                              hipStream_t stream) {
    const float* x   = (const float*)d_in[0];        // [B, L, D] fp32
    const int*   dur = (const int*)d_in[1];          // [B, L] int32
    // d_in[2] = mel_max_length scalar (static 4096; hard-coded)
    float* out  = (float*)d_out;                      // [B, TMAX, D] fp32
    int*   ends = (int*)d_ws;                         // [B, L] int32 (32 KB scratch)

    MRTE_cumsum_kernel<<<BATCH, LTOK, 0, stream>>>(dur, ends);
    MRTE_gather_kernel<<<dim3(TMAX / ROWS, BATCH), 256, 0, stream>>>(x, ends, out);
}

// Round 6
// 156.391 us; speedup vs baseline: 1.0243x; 1.0184x over previous
//
#include <hip/hip_runtime.h>

// LengthRegulator: out[b, t, :] = x[b, j, :] where j = searchsorted(cumsum(dur[b]), t, 'right'),
// zero for t >= total duration. B=16, L=512, D=512, T_MAX=4096. fp32 in/out.
// R6: single fused kernel. Wave 0 of every block redundantly computes the
// inclusive cumsum of its batch's 512 durations (8 elems/lane local scan +
// 64-lane shfl scan) straight into LDS — kills the separate cumsum launch and
// its dependency drain (~4-5 us of serial overhead in a ~34 us controllable
// window). Gather: 8 rows/block, per-thread monotone token cursor, 16B lanes,
// nontemporal streaming stores for the write-once 128 MB output.

#define BATCH 16
#define LTOK  512
#define DIM   512
#define TMAX  4096
#define ROWS  8   // output rows per gather block

typedef float nt_f4 __attribute__((ext_vector_type(4)));  // 16B, same layout as float4

__global__ __launch_bounds__(256) void MRTE_fused_kernel(const float* __restrict__ x,
                                                         const int* __restrict__ dur,
                                                         float* __restrict__ out) {
    __shared__ int se[LTOK];
    const int b    = blockIdx.y;
    const int t0   = blockIdx.x * ROWS;
    const int tid  = threadIdx.x;
    const int half = tid >> 7;    // 0 or 1: which row of the pair
    const int lane = tid & 127;   // 16B column (128 * 16B = 2KB row)

    // ---- wave 0: inclusive cumsum of dur[b][0..511] into se[] ----
    if (tid < 64) {
        const int4* __restrict__ d4 = reinterpret_cast<const int4*>(dur + b * LTOK);
        int4 a = d4[tid * 2];
        int4 c = d4[tid * 2 + 1];
        int p0 = a.x;
        int p1 = p0 + a.y;
        int p2 = p1 + a.z;
        int p3 = p2 + a.w;
        int p4 = p3 + c.x;
        int p5 = p4 + c.y;
        int p6 = p5 + c.z;
        int p7 = p6 + c.w;
        int s = p7;
        #pragma unroll
        for (int off = 1; off < 64; off <<= 1) {   // 64-lane inclusive shfl scan
            int n = __shfl_up(s, off, 64);
            if (tid >= off) s += n;
        }
        const int base = s - p7;                    // exclusive prefix of this lane's chunk
        int4* o = reinterpret_cast<int4*>(se + tid * 8);
        o[0] = make_int4(base + p0, base + p1, base + p2, base + p3);
        o[1] = make_int4(base + p4, base + p5, base + p6, base + p7);
    }
    __syncthreads();

    const int total = se[LTOK - 1];

    // first j with se[j] > t0 (block-uniform; LDS broadcast reads)
    int lo = 0, hi = LTOK;
    while (lo < hi) {
        int mid = (lo + hi) >> 1;
        if (se[mid] > t0) hi = mid; else lo = mid + 1;
    }

    const nt_f4* __restrict__ xb =
        reinterpret_cast<const nt_f4*>(x + (size_t)b * LTOK * DIM);
    nt_f4* __restrict__ ob =
        reinterpret_cast<nt_f4*>(out + ((size_t)b * TMAX + (size_t)t0) * DIM);

    int jt = lo;  // per-thread token cursor, monotone over this thread's rows
    #pragma unroll
    for (int r = 0; r < ROWS; r += 2) {
        const int t = t0 + r + half;
        nt_f4 v = (nt_f4)0.f;
        if (t < total) {
            while (se[jt] <= t) ++jt;          // avg ~2 LDS-hit steps per chunk
            v = xb[(size_t)jt * (DIM / 4) + lane];
        }
        __builtin_nontemporal_store(v, &ob[(size_t)(r + half) * (DIM / 4) + lane]);
    }
}

extern "C" void kernel_launch(void* const* d_in, const int* in_sizes, int n_in,
                              void* d_out, int out_size, void* d_ws, size_t ws_size,
                              hipStream_t stream) {
    const float* x   = (const float*)d_in[0];        // [B, L, D] fp32
    const int*   dur = (const int*)d_in[1];          // [B, L] int32
    // d_in[2] = mel_max_length scalar (static 4096; hard-coded)
    float* out = (float*)d_out;                       // [B, TMAX, D] fp32

    MRTE_fused_kernel<<<dim3(TMAX / ROWS, BATCH), 256, 0, stream>>>(x, dur, out);
}